// Round 8
// baseline (795.867 us; speedup 1.0000x reference)
//
#include <hip/hip_runtime.h>
#include <math.h>

// ---------------- problem constants (ANI-2x) ----------------
constexpr int SPEC = 7;
constexpr int DAEV = 1008;
constexpr int RADN = 112;
constexpr int H1W = 256, H2W = 192, H3W = 160;
constexpr int MENS = 8;
constexpr float ALPHA = 0.1f;
constexpr float RCR_ = 5.2f, RCA_ = 3.5f;
constexpr float ETAR = 19.7f, ETAA = 12.5f, ZETA_ = 14.1f;
constexpr float PIF = 3.14159265358979323846f;

enum { MODE_FWD = 0, MODE_BWD = 1, MODE_PLAIN = 2 };

typedef _Float16 f16x8 __attribute__((ext_vector_type(8)));
typedef float f32x4 __attribute__((ext_vector_type(4)));

__device__ __forceinline__ f32x4 mfma16(f16x8 a, f16x8 b, f32x4 c) {
    return __builtin_amdgcn_mfma_f32_16x16x32_f16(a, b, c, 0, 0, 0);
}

__device__ __forceinline__ void cvt8(float4 u0, float4 u1, f16x8& h, f16x8& l) {
    float x[8] = {u0.x, u0.y, u0.z, u0.w, u1.x, u1.y, u1.z, u1.w};
    #pragma unroll
    for (int e = 0; e < 8; ++e) {
        _Float16 hh = (_Float16)x[e];
        h[e] = hh;
        l[e] = (_Float16)(x[e] - (float)hh);
    }
}

// ---------------- species-list build ----------------
__global__ __launch_bounds__(256) void build_lists_k(
    const int* __restrict__ sgp, int* __restrict__ counts,
    int* __restrict__ lists, int N)
{
    int n = blockIdx.x * blockDim.x + threadIdx.x;
    if (n >= N) return;
    int g = sgp[n];
    if (g >= 0) {
        int p = atomicAdd(&counts[g], 1);
        lists[g * N + p] = n;
    }
}

// ---------------- AEV radial forward ----------------
__global__ __launch_bounds__(256) void radial_fwd_k(
    const int* __restrict__ ai12, const int* __restrict__ spec,
    const float* __restrict__ coord, float* __restrict__ aev, int P)
{
    int p = blockIdx.x * blockDim.x + threadIdx.x;
    if (p >= P) return;
    int i = ai12[p], j = ai12[P + p];
    float dx = coord[3 * j + 0] - coord[3 * i + 0];
    float dy = coord[3 * j + 1] - coord[3 * i + 1];
    float dz = coord[3 * j + 2] - coord[3 * i + 2];
    float d = sqrtf(dx * dx + dy * dy + dz * dz);
    float fc = (d < RCR_) ? (0.5f * cosf(PIF * d / RCR_) + 0.5f) : 0.f;
    int spi = spec[i], spj = spec[j];
    float* bi = aev + (size_t)i * DAEV + spj * 16;
    float* bj = aev + (size_t)j * DAEV + spi * 16;
    #pragma unroll
    for (int k = 0; k < 16; ++k) {
        float sh = 0.8f + 0.275f * k;
        float t = d - sh;
        float v = 0.25f * expf(-ETAR * t * t) * fc;
        atomicAdd(bi + k, v);
        atomicAdd(bj + k, v);
    }
}

// ---------------- AEV angular forward ----------------
__global__ __launch_bounds__(256) void angular_fwd_k(
    const int* __restrict__ tri, const int* __restrict__ spec,
    const float* __restrict__ coord, float* __restrict__ aev, int T)
{
    int t = blockIdx.x * blockDim.x + threadIdx.x;
    if (t >= T) return;
    int c = tri[t], a = tri[T + t], b = tri[2 * T + t];
    float cx = coord[3 * c], cy = coord[3 * c + 1], cz = coord[3 * c + 2];
    float v1x = coord[3 * a] - cx, v1y = coord[3 * a + 1] - cy, v1z = coord[3 * a + 2] - cz;
    float v2x = coord[3 * b] - cx, v2y = coord[3 * b + 1] - cy, v2z = coord[3 * b + 2] - cz;
    float d1 = sqrtf(v1x * v1x + v1y * v1y + v1z * v1z);
    float d2 = sqrtf(v2x * v2x + v2y * v2y + v2z * v2z);
    float u = v1x * v2x + v1y * v2y + v1z * v2z;
    float ca = 0.95f * u / (d1 * d2);
    float sa = sqrtf(fmaxf(1.f - ca * ca, 0.f));
    float fc1 = (d1 < RCA_) ? (0.5f * cosf(PIF * d1 / RCA_) + 0.5f) : 0.f;
    float fc2 = (d2 < RCA_) ? (0.5f * cosf(PIF * d2 / RCA_) + 0.5f) : 0.f;
    float fcj = fc1 * fc2;
    float savg = 0.5f * (d1 + d2);
    int s1 = spec[a], s2 = spec[b];
    int lo = min(s1, s2), hi = max(s1, s2);
    int pidx = lo * SPEC - (lo * (lo - 1)) / 2 + (hi - lo);
    float* ob = aev + (size_t)c * DAEV + RADN + pidx * 32;
    const float CZ[4] = {0.92387953f, 0.38268343f, -0.38268343f, -0.92387953f};
    const float SZ[4] = {0.38268343f, 0.92387953f, 0.92387953f, 0.38268343f};
    float f1[4];
    #pragma unroll
    for (int zz = 0; zz < 4; ++zz) {
        float cd = ca * CZ[zz] + sa * SZ[zz];
        float base = fmaxf(0.5f * (1.f + cd), 0.f);
        f1[zz] = powf(base, ZETA_);
    }
    #pragma unroll
    for (int q = 0; q < 8; ++q) {
        float sh = 0.8f + 0.3375f * q;
        float tq = savg - sh;
        float f2 = expf(-ETAA * tq * tq);
        float b2 = 2.f * f2 * fcj;
        #pragma unroll
        for (int zz = 0; zz < 4; ++zz)
            atomicAdd(ob + q * 4 + zz, b2 * f1[zz]);
    }
}

// ---------------- weight convert: fp32 -> hi/lo f16 ----------------
template<bool DO_O, bool DO_T>
__global__ __launch_bounds__(256) void wconv_k(
    const float* __restrict__ W,
    _Float16* __restrict__ oH, _Float16* __restrict__ oL,
    _Float16* __restrict__ tH, _Float16* __restrict__ tL,
    int K, int C, int ldt)
{
    __shared__ _Float16 sh[64][65];
    __shared__ _Float16 sl[64][65];
    const int z = blockIdx.z;
    const int k0 = blockIdx.y * 64, c0 = blockIdx.x * 64;
    const float* Wz = W + (size_t)z * K * C;
    const int c = threadIdx.x & 63, qr = threadIdx.x >> 6;
    #pragma unroll
    for (int rr = 0; rr < 16; ++rr) {
        int r = qr * 16 + rr;
        int k = k0 + r, cc = c0 + c;
        float v = (k < K && cc < C) ? Wz[(size_t)k * C + cc] : 0.f;
        _Float16 h = (_Float16)v;
        _Float16 l = (_Float16)(v - (float)h);
        if (DO_O && k < K && cc < C) {
            oH[(size_t)z * K * C + (size_t)k * C + cc] = h;
            oL[(size_t)z * K * C + (size_t)k * C + cc] = l;
        }
        if (DO_T) { sh[r][c] = h; sl[r][c] = l; }
    }
    if (DO_T) {
        __syncthreads();
        #pragma unroll
        for (int rr = 0; rr < 16; ++rr) {
            int r = qr * 16 + rr;
            int crow = c0 + r, kcol = k0 + c;
            if (crow < C && kcol < ldt) {
                tH[(size_t)z * C * ldt + (size_t)crow * ldt + kcol] = sh[c][r];
                tL[(size_t)z * C * ldt + (size_t)crow * ldt + kcol] = sl[c][r];
            }
        }
    }
}

// ---------------- MFMA fp16x3-split GEMM, 8-wave in-block split-K ----------------
// Block 64 rows x 128 cols; 512 threads = 2 k-groups x 4 waves (2x2, 32x64 each).
// Group g covers its half of the K range; partial accs combined via LDS.
// ASRC/BSRC/SPLITK semantics as before. XCD z-swizzle when gridDim.z==56.
template<int MODE, int ASRC, int BSRC, bool MCONCAT, int SPLITK>
__global__ __launch_bounds__(512) void mgemm_k(
    const void* __restrict__ Ah_, const void* __restrict__ Al_,
    const void* __restrict__ Bh_, const void* __restrict__ Bl_,
    const float* __restrict__ bias, float* __restrict__ cF,
    _Float16* __restrict__ cH, _Float16* __restrict__ cL,
    const int* __restrict__ lists, const int* __restrict__ counts,
    int N, int K, int KA, int H, int lda, int ldb, int ldc,
    size_t aStrM, size_t bStrZ, size_t cStrM)
{
    // LDS: A 2x[4][64], B 2x[4][128], hi+lo -> 3072 f16x8 = 48 KB
    __shared__ f16x8 SM[3072];
    __shared__ int atomsS[64];
    #define AhS(g, kq, i) SM[(g) * 256 + (kq) * 64 + (i)]
    #define AlS(g, kq, i) SM[512 + (g) * 256 + (kq) * 64 + (i)]
    #define BhS(g, kq, c) SM[1024 + (g) * 512 + (kq) * 128 + (c)]
    #define BlS(g, kq, c) SM[2048 + (g) * 512 + (kq) * 128 + (c)]

    // ---- XCD-aware z-swizzle (bijective for gridDim.z == 56) ----
    int bx = blockIdx.x, by = blockIdx.y, bz = blockIdx.z;
    if (gridDim.z == 56) {
        int BXY = gridDim.x * gridDim.y;
        int flat = bx + gridDim.x * (by + gridDim.y * bz);
        int xcd = flat & 7;
        int rest = flat >> 3;
        int zw = rest / BXY;
        int xy = rest - zw * BXY;
        bz = xcd * 7 + zw;
        bx = xy % gridDim.x;
        by = xy / gridDim.x;
    }

    const int z = bz;
    int m, sp_, chunk;
    if (MCONCAT) {
        sp_ = (SPLITK > 1) ? (z % SPEC) : z;
        chunk = (SPLITK > 1) ? (z / SPEC) : 0;
        m = 0;
    } else {
        m = z / SPEC; sp_ = z - m * SPEC; chunk = 0;
    }
    const int cnt = counts[sp_];
    const int row0 = by * 64;
    if (row0 >= cnt) return;
    const int col0 = bx * 128;
    const int tid = threadIdx.x;
    const int w = tid >> 6, lane = tid & 63;
    const int g = w >> 2, wl = w & 3;

    const int rA = min(row0 + lane, cnt - 1);
    const int atomA = lists[sp_ * N + rA];
    if (tid < 64) atomsS[tid] = atomA;

    const int bc0 = min(col0 + lane, H - 1);
    const int bc1 = min(col0 + 64 + lane, H - 1);

    f16x8 rAh, rAl;
    float4 rAf0, rAf1;
    f16x8 rBh0, rBl0, rBh1, rBl1;
    float4 rBq[4];
    float rB0f[8], rB1f[8];

    auto LOAD = [&](int k0s) {
        int kk = k0s + wl * 8;
        // ---- A ----
        if constexpr (ASRC == 0) {
            const _Float16* ah = (const _Float16*)Ah_;
            const _Float16* al = (const _Float16*)Al_;
            size_t ao;
            if constexpr (MCONCAT) {
                int mm = kk >> 8, kr = kk & 255;
                ao = ((size_t)mm * N + atomA) * (size_t)lda + kr;
            } else {
                ao = (size_t)m * aStrM + (size_t)atomA * lda + kk;
            }
            rAh = *(const f16x8*)(ah + ao);
            rAl = *(const f16x8*)(al + ao);
        } else {
            const float* af = (const float*)Ah_;
            if (kk < KA) {
                const float* p = af + (size_t)atomA * lda + kk;
                rAf0 = *(const float4*)p;
                rAf1 = *(const float4*)(p + 4);
            } else {
                rAf0 = make_float4(0.f, 0.f, 0.f, 0.f);
                rAf1 = rAf0;
            }
        }
        // ---- B ----
        if constexpr (BSRC == 0) {
            const _Float16* bh = (const _Float16*)Bh_;
            const _Float16* bl = (const _Float16*)Bl_;
            size_t b0 = (size_t)z * bStrZ + (size_t)bc0 * ldb + kk;
            size_t b1 = (size_t)z * bStrZ + (size_t)bc1 * ldb + kk;
            rBh0 = *(const f16x8*)(bh + b0);
            rBh1 = *(const f16x8*)(bh + b1);
            rBl0 = *(const f16x8*)(bl + b0);
            rBl1 = *(const f16x8*)(bl + b1);
        } else if constexpr (BSRC == 1) {
            const float* bf = (const float*)Bh_;
            int mm = kk >> 8, kr = kk & 255;   // MCONCAT layout
            size_t b0 = ((size_t)(mm * SPEC + sp_) * DAEV + bc0) * (size_t)ldb + kr;
            size_t b1 = ((size_t)(mm * SPEC + sp_) * DAEV + bc1) * (size_t)ldb + kr;
            rBq[0] = *(const float4*)(bf + b0);
            rBq[1] = *(const float4*)(bf + b0 + 4);
            rBq[2] = *(const float4*)(bf + b1);
            rBq[3] = *(const float4*)(bf + b1 + 4);
        } else {
            // fp32 [k][c]: lane=col -> coalesced 256B segments per k
            const float* bf = (const float*)Bh_ + (size_t)z * bStrZ;
            #pragma unroll
            for (int j = 0; j < 8; ++j) {
                int kg = kk + j;
                float v0 = 0.f, v1 = 0.f;
                if (kg < KA) {
                    v0 = bf[(size_t)kg * ldb + bc0];
                    v1 = bf[(size_t)kg * ldb + bc1];
                }
                rB0f[j] = v0;
                rB1f[j] = v1;
            }
        }
    };

    auto WRITE = [&]() {
        if constexpr (ASRC == 0) {
            AhS(g, wl, lane) = rAh;
            AlS(g, wl, lane) = rAl;
        } else {
            f16x8 h, l;
            cvt8(rAf0, rAf1, h, l);
            AhS(g, wl, lane) = h;
            AlS(g, wl, lane) = l;
        }
        if constexpr (BSRC == 0) {
            BhS(g, wl, lane) = rBh0;
            BhS(g, wl, 64 + lane) = rBh1;
            BlS(g, wl, lane) = rBl0;
            BlS(g, wl, 64 + lane) = rBl1;
        } else if constexpr (BSRC == 1) {
            f16x8 h, l;
            cvt8(rBq[0], rBq[1], h, l);
            BhS(g, wl, lane) = h;
            BlS(g, wl, lane) = l;
            cvt8(rBq[2], rBq[3], h, l);
            BhS(g, wl, 64 + lane) = h;
            BlS(g, wl, 64 + lane) = l;
        } else {
            f16x8 h0, l0, h1, l1;
            #pragma unroll
            for (int j = 0; j < 8; ++j) {
                _Float16 ha = (_Float16)rB0f[j];
                h0[j] = ha; l0[j] = (_Float16)(rB0f[j] - (float)ha);
                _Float16 hb = (_Float16)rB1f[j];
                h1[j] = hb; l1[j] = (_Float16)(rB1f[j] - (float)hb);
            }
            BhS(g, wl, lane) = h0;
            BlS(g, wl, lane) = l0;
            BhS(g, wl, 64 + lane) = h1;
            BlS(g, wl, 64 + lane) = l1;
        }
    };

    const int wr = wl >> 1, wc = wl & 1;
    const int fr = lane & 15, q = lane >> 4;

    f32x4 acc[2][4];
    #pragma unroll
    for (int mi = 0; mi < 2; ++mi)
        #pragma unroll
        for (int ni = 0; ni < 4; ++ni)
            acc[mi][ni] = (f32x4){0.f, 0.f, 0.f, 0.f};

    // per-group K range within this block's (grid-level) K chunk
    const int KC = (SPLITK > 1) ? (K / SPLITK) : K;
    const int kbeg = chunk * KC;
    const int ntT = KC / 32;
    const int nt0 = (ntT + 1) >> 1;
    const int my_nt = g ? (ntT - nt0) : nt0;
    const int gk = kbeg + (g ? nt0 * 32 : 0);

    if (my_nt > 0) LOAD(gk);

    for (int t = 0; t < nt0; ++t) {
        __syncthreads();                 // consumers of previous LDS tile done
        if (t < my_nt) WRITE();
        __syncthreads();                 // tile t visible
        if (t + 1 < my_nt) LOAD(gk + (t + 1) * 32);

        if (t < my_nt) {
            f16x8 fah[2], fal[2], fbh[4], fbl[4];
            #pragma unroll
            for (int mi = 0; mi < 2; ++mi) {
                int r = wr * 32 + mi * 16 + fr;
                fah[mi] = AhS(g, q, r);
                fal[mi] = AlS(g, q, r);
            }
            #pragma unroll
            for (int ni = 0; ni < 4; ++ni) {
                int c = wc * 64 + ni * 16 + fr;
                fbh[ni] = BhS(g, q, c);
                fbl[ni] = BlS(g, q, c);
            }
            #pragma unroll
            for (int mi = 0; mi < 2; ++mi)
                #pragma unroll
                for (int ni = 0; ni < 4; ++ni) {
                    acc[mi][ni] = mfma16(fah[mi], fbl[ni], acc[mi][ni]);
                    acc[mi][ni] = mfma16(fal[mi], fbh[ni], acc[mi][ni]);
                    acc[mi][ni] = mfma16(fah[mi], fbh[ni], acc[mi][ni]);
                }
        }
    }

    // ---- combine the two k-groups' partial accumulators via LDS ----
    __syncthreads();
    f32x4* X = (f32x4*)SM;               // 2048 entries = 32 KB, fits in 48 KB
    const int xbase = (wl * 64 + lane) * 8;
    if (g == 1) {
        #pragma unroll
        for (int mi = 0; mi < 2; ++mi)
            #pragma unroll
            for (int ni = 0; ni < 4; ++ni)
                X[xbase + mi * 4 + ni] = acc[mi][ni];
    }
    __syncthreads();
    if (g == 1) return;                  // no more barriers below
    #pragma unroll
    for (int mi = 0; mi < 2; ++mi)
        #pragma unroll
        for (int ni = 0; ni < 4; ++ni) {
            f32x4 o = X[xbase + mi * 4 + ni];
            acc[mi][ni] += o;
        }

    // ---- epilogue (group 0 only) ----
    const float* brow = (MODE == MODE_FWD) ? (bias + (size_t)z * H) : nullptr;
    #pragma unroll
    for (int mi = 0; mi < 2; ++mi) {
        #pragma unroll
        for (int r = 0; r < 4; ++r) {
            int rl = wr * 32 + mi * 16 + q * 4 + r;
            if (row0 + rl >= cnt) continue;
            int atom = atomsS[rl];
            size_t rowoff = (size_t)m * cStrM + (size_t)atom * ldc;
            #pragma unroll
            for (int ni = 0; ni < 4; ++ni) {
                int col = col0 + wc * 64 + ni * 16 + fr;
                if (col >= H) continue;
                float v = acc[mi][ni][r];
                size_t idx = rowoff + col;
                if (MODE == MODE_FWD) {
                    v += brow[col];
                    v = (v > 0.f) ? v : ALPHA * expm1f(v * (1.f / ALPHA));
                    _Float16 hh = (_Float16)v;
                    cH[idx] = hh;
                    cL[idx] = (_Float16)(v - (float)hh);
                } else if (MODE == MODE_BWD) {
                    float hprev = (float)cH[idx] + (float)cL[idx];
                    float D = (hprev > 0.f) ? 1.f : (hprev * (1.f / ALPHA) + 1.f);
                    v *= D;
                    _Float16 hh = (_Float16)v;
                    cH[idx] = hh;
                    cL[idx] = (_Float16)(v - (float)hh);
                } else {
                    if (SPLITK > 1) atomicAdd(cF + idx, v);
                    else cF[idx] = v;
                }
            }
        }
    }
    #undef AhS
    #undef AlS
    #undef BhS
    #undef BlS
}

// ---------------- layer-4 dot + energy + dh3 (in place) ----------------
__global__ __launch_bounds__(256) void l4_k(
    _Float16* __restrict__ h3H, _Float16* __restrict__ h3L,
    const float* __restrict__ W4, const float* __restrict__ b4,
    const int* __restrict__ lists, const int* __restrict__ counts,
    float* __restrict__ Eout, int N)
{
    const int z = blockIdx.y;
    const int m = z / SPEC, s = z - m * SPEC;
    const int cnt = counts[s];
    const int sub = threadIdx.x >> 3;
    const int l8 = threadIdx.x & 7;
    const int row = blockIdx.x * 32 + sub;

    __shared__ float bsum;
    if (threadIdx.x == 0) bsum = 0.f;
    __syncthreads();

    if (row < cnt) {
        int atom = lists[s * N + row];
        size_t base = ((size_t)m * N + atom) * H3W;
        const float* w4 = W4 + (size_t)z * H3W;
        float sum = 0.f;
        for (int k = l8; k < H3W; k += 8) {
            float h = (float)h3H[base + k] + (float)h3L[base + k];
            float wv = w4[k];
            sum += h * wv;
            float D = (h > 0.f) ? 1.f : (h * 10.f + 1.f);
            float g = 0.125f * wv * D;
            _Float16 gh = (_Float16)g;
            h3H[base + k] = gh;
            h3L[base + k] = (_Float16)(g - (float)gh);
        }
        sum += __shfl_xor(sum, 1);
        sum += __shfl_xor(sum, 2);
        sum += __shfl_xor(sum, 4);
        if (l8 == 0) atomicAdd(&bsum, sum + b4[z]);
    }
    __syncthreads();
    if (threadIdx.x == 0) atomicAdd(Eout, 0.125f * bsum);
}

// ---------------- AEV radial backward ----------------
__global__ __launch_bounds__(256) void radial_bwd_k(
    const int* __restrict__ ai12, const int* __restrict__ spec,
    const float* __restrict__ coord, const float* __restrict__ daev,
    float* __restrict__ grad, int P)
{
    int p = blockIdx.x * blockDim.x + threadIdx.x;
    if (p >= P) return;
    int i = ai12[p], j = ai12[P + p];
    float dx = coord[3 * j + 0] - coord[3 * i + 0];
    float dy = coord[3 * j + 1] - coord[3 * i + 1];
    float dz = coord[3 * j + 2] - coord[3 * i + 2];
    float d = sqrtf(dx * dx + dy * dy + dz * dz);
    float fc, dfc;
    if (d < RCR_) {
        float ph = PIF * d / RCR_;
        fc = 0.5f * cosf(ph) + 0.5f;
        dfc = -0.5f * sinf(ph) * (PIF / RCR_);
    } else { fc = 0.f; dfc = 0.f; }
    int spi = spec[i], spj = spec[j];
    const float* gi = daev + (size_t)i * DAEV + spj * 16;
    const float* gj = daev + (size_t)j * DAEV + spi * 16;
    float gs = 0.f;
    #pragma unroll
    for (int k = 0; k < 16; ++k) {
        float sh = 0.8f + 0.275f * k;
        float t = d - sh;
        float ex = expf(-ETAR * t * t);
        float g = gi[k] + gj[k];
        gs += g * 0.25f * ex * (dfc - 2.f * ETAR * t * fc);
    }
    float invd = 1.f / d;
    float gx = gs * dx * invd, gy = gs * dy * invd, gz = gs * dz * invd;
    atomicAdd(&grad[3 * j + 0], gx);  atomicAdd(&grad[3 * j + 1], gy);  atomicAdd(&grad[3 * j + 2], gz);
    atomicAdd(&grad[3 * i + 0], -gx); atomicAdd(&grad[3 * i + 1], -gy); atomicAdd(&grad[3 * i + 2], -gz);
}

// ---------------- AEV angular backward ----------------
__global__ __launch_bounds__(256) void angular_bwd_k(
    const int* __restrict__ tri, const int* __restrict__ spec,
    const float* __restrict__ coord, const float* __restrict__ daev,
    float* __restrict__ grad, int T)
{
    int t = blockIdx.x * blockDim.x + threadIdx.x;
    if (t >= T) return;
    int c = tri[t], a = tri[T + t], b = tri[2 * T + t];
    float cx = coord[3 * c], cy = coord[3 * c + 1], cz = coord[3 * c + 2];
    float v1x = coord[3 * a] - cx, v1y = coord[3 * a + 1] - cy, v1z = coord[3 * a + 2] - cz;
    float v2x = coord[3 * b] - cx, v2y = coord[3 * b + 1] - cy, v2z = coord[3 * b + 2] - cz;
    float d1 = sqrtf(v1x * v1x + v1y * v1y + v1z * v1z);
    float d2 = sqrtf(v2x * v2x + v2y * v2y + v2z * v2z);
    float u = v1x * v2x + v1y * v2y + v1z * v2z;
    float inv12 = 1.f / (d1 * d2);
    float ca = 0.95f * u * inv12;
    float sa = sqrtf(fmaxf(1.f - ca * ca, 1e-12f));
    float fc1, dfc1, fc2, dfc2;
    if (d1 < RCA_) {
        float ph = PIF * d1 / RCA_;
        fc1 = 0.5f * cosf(ph) + 0.5f;
        dfc1 = -0.5f * sinf(ph) * (PIF / RCA_);
    } else { fc1 = 0.f; dfc1 = 0.f; }
    if (d2 < RCA_) {
        float ph = PIF * d2 / RCA_;
        fc2 = 0.5f * cosf(ph) + 0.5f;
        dfc2 = -0.5f * sinf(ph) * (PIF / RCA_);
    } else { fc2 = 0.f; dfc2 = 0.f; }
    float fcj = fc1 * fc2;
    float savg = 0.5f * (d1 + d2);
    int s1 = spec[a], s2 = spec[b];
    int lo = min(s1, s2), hi = max(s1, s2);
    int pidx = lo * SPEC - (lo * (lo - 1)) / 2 + (hi - lo);
    const float* gb = daev + (size_t)c * DAEV + RADN + pidx * 32;
    const float CZ[4] = {0.92387953f, 0.38268343f, -0.38268343f, -0.92387953f};
    const float SZ[4] = {0.38268343f, 0.92387953f, 0.92387953f, 0.38268343f};
    float f1[4], df1[4];
    #pragma unroll
    for (int zz = 0; zz < 4; ++zz) {
        float cd = ca * CZ[zz] + sa * SZ[zz];
        float sd = sa * CZ[zz] - ca * SZ[zz];
        float base = fmaxf(0.5f * (1.f + cd), 0.f);
        float pm1 = powf(base, ZETA_ - 1.f);
        f1[zz] = pm1 * base;
        df1[zz] = ZETA_ * pm1 * (-0.5f * sd);
    }
    float A_ = 0.f, B_ = 0.f, Cc = 0.f;
    #pragma unroll
    for (int q = 0; q < 8; ++q) {
        float sh = 0.8f + 0.3375f * q;
        float tq = savg - sh;
        float f2 = expf(-ETAA * tq * tq);
        float df2 = -ETAA * tq * f2;
        #pragma unroll
        for (int zz = 0; zz < 4; ++zz) {
            float G2 = 2.f * gb[q * 4 + zz];
            A_ += G2 * f2 * df1[zz];
            B_ += G2 * df2 * f1[zz];
            Cc += G2 * f2 * f1[zz];
        }
    }
    A_ *= fcj; B_ *= fcj;
    float C1 = Cc * dfc1 * fc2;
    float C2 = Cc * fc1 * dfc2;
    float cA = -A_ / sa;
    float k12 = cA * 0.95f * inv12;
    float coef1 = (cA * (-ca) / d1 + B_ + C1) / d1;
    float coef2 = (cA * (-ca) / d2 + B_ + C2) / d2;
    float g1x = coef1 * v1x + k12 * v2x;
    float g1y = coef1 * v1y + k12 * v2y;
    float g1z = coef1 * v1z + k12 * v2z;
    float g2x = coef2 * v2x + k12 * v1x;
    float g2y = coef2 * v2y + k12 * v1y;
    float g2z = coef2 * v2z + k12 * v1z;
    atomicAdd(&grad[3 * a + 0], g1x); atomicAdd(&grad[3 * a + 1], g1y); atomicAdd(&grad[3 * a + 2], g1z);
    atomicAdd(&grad[3 * b + 0], g2x); atomicAdd(&grad[3 * b + 1], g2y); atomicAdd(&grad[3 * b + 2], g2z);
    atomicAdd(&grad[3 * c + 0], -(g1x + g2x));
    atomicAdd(&grad[3 * c + 1], -(g1y + g2y));
    atomicAdd(&grad[3 * c + 2], -(g1z + g2z));
}

// ---------------- finalize: forces out, SAE into E ----------------
__global__ __launch_bounds__(256) void finalize_k(
    const float* __restrict__ grad, const int* __restrict__ sgp,
    const float* __restrict__ sae, float* __restrict__ out, int N)
{
    int n = blockIdx.x * blockDim.x + threadIdx.x;
    __shared__ float bs;
    if (threadIdx.x == 0) bs = 0.f;
    __syncthreads();
    float v = 0.f;
    if (n < N) {
        out[1 + 3 * n + 0] = -grad[3 * n + 0];
        out[1 + 3 * n + 1] = -grad[3 * n + 1];
        out[1 + 3 * n + 2] = -grad[3 * n + 2];
        int g = sgp[n];
        if (g >= 0) v = sae[g];
    }
    atomicAdd(&bs, v);
    __syncthreads();
    if (threadIdx.x == 0) atomicAdd(out, bs);
}

// ---------------- host launch ----------------
extern "C" void kernel_launch(void* const* d_in, const int* in_sizes, int n_in,
                              void* d_out, int out_size, void* d_ws, size_t ws_size,
                              hipStream_t stream)
{
    (void)n_in; (void)out_size; (void)ws_size;
    const int* species = (const int*)d_in[0];
    const float* coords = (const float*)d_in[1];
    const int* ai12 = (const int*)d_in[2];
    const int* tri = (const int*)d_in[3];
    const int* sgp = (const int*)d_in[4];
    const float* W1 = (const float*)d_in[5];
    const float* b1 = (const float*)d_in[6];
    const float* W2 = (const float*)d_in[7];
    const float* b2 = (const float*)d_in[8];
    const float* W3 = (const float*)d_in[9];
    const float* b3 = (const float*)d_in[10];
    const float* W4 = (const float*)d_in[11];
    const float* b4 = (const float*)d_in[12];
    const float* sae = (const float*)d_in[13];
    float* out = (float*)d_out;

    const int N = in_sizes[0];
    const int P = in_sizes[2] / 2;
    const int T = in_sizes[3] / 3;
    const size_t NM = (size_t)MENS * N;

    float* ws = (float*)d_ws;
    size_t off = 0;
    auto alloc = [&](size_t nf) { float* p = ws + off; off += nf; return p; };

    // total ~75.6 MB == R2's proven-safe footprint
    float* aev = alloc((size_t)N * DAEV);              // reused as daev after L1 fwd
    _Float16* H1h = (_Float16*)alloc(NM * 128);        // d1 written in place
    _Float16* H1l = (_Float16*)alloc(NM * 128);
    _Float16* H2h = (_Float16*)alloc(NM * 96);         // d2 in place
    _Float16* H2l = (_Float16*)alloc(NM * 96);
    _Float16* H3h = (_Float16*)alloc(NM * 80);         // d3 in place
    _Float16* H3l = (_Float16*)alloc(NM * 80);
    // one shared W buffer (W2-sized), reconverted between uses: W2t->W3t->W3o->W2o
    _Float16* Wh = (_Float16*)alloc((size_t)56 * 96 * 256);
    _Float16* Wl = (_Float16*)alloc((size_t)56 * 96 * 256);
    float* grad = alloc((size_t)N * 3);
    int* counts = (int*)alloc(8);
    int* lists = (int*)alloc((size_t)SPEC * N);
    float* daev = aev;

    hipMemsetAsync(aev, 0, (size_t)N * DAEV * sizeof(float), stream);
    hipMemsetAsync(grad, 0, (size_t)N * 3 * sizeof(float), stream);
    hipMemsetAsync(counts, 0, 8 * sizeof(int), stream);
    hipMemsetAsync(d_out, 0, sizeof(float), stream);

    build_lists_k<<<(N + 255) / 256, 256, 0, stream>>>(sgp, counts, lists, N);
    radial_fwd_k<<<(P + 255) / 256, 256, 0, stream>>>(ai12, species, coords, aev, P);
    angular_fwd_k<<<(T + 255) / 256, 256, 0, stream>>>(tri, species, coords, aev, T);

    const int rt = (N + 63) / 64;

    // L1 fwd: H1 = celu(AEV @ W1 + b1); A fp32 (aev), B fp32 W1 [k][c] coalesced
    mgemm_k<MODE_FWD, 1, 2, false, 1><<<dim3(2, rt, 56), 512, 0, stream>>>(
        aev, nullptr, W1, nullptr, b1, nullptr, H1h, H1l,
        lists, counts, N, 1024, 1008, 256, 1008, 256, 256,
        0, (size_t)1008 * 256, (size_t)N * 256);

    // W2 -> t-layout (for L2 fwd)
    wconv_k<false, true><<<dim3(3, 4, 56), 256, 0, stream>>>(
        W2, nullptr, nullptr, Wh, Wl, 256, 192, 256);
    // L2 fwd
    mgemm_k<MODE_FWD, 0, 0, false, 1><<<dim3(2, rt, 56), 512, 0, stream>>>(
        H1h, H1l, Wh, Wl, b2, nullptr, H2h, H2l,
        lists, counts, N, 256, 256, 192, 256, 256, 192,
        (size_t)N * 256, (size_t)192 * 256, (size_t)N * 192);

    // W3 -> t-layout (for L3 fwd)
    wconv_k<false, true><<<dim3(3, 3, 56), 256, 0, stream>>>(
        W3, nullptr, nullptr, Wh, Wl, 192, 160, 192);
    // L3 fwd
    mgemm_k<MODE_FWD, 0, 0, false, 1><<<dim3(2, rt, 56), 512, 0, stream>>>(
        H2h, H2l, Wh, Wl, b3, nullptr, H3h, H3l,
        lists, counts, N, 192, 192, 160, 192, 192, 160,
        (size_t)N * 192, (size_t)160 * 192, (size_t)N * 160);

    // L4 + dh3 (in place in H3)
    l4_k<<<dim3((N + 31) / 32, 56), 256, 0, stream>>>(
        H3h, H3l, W4, b4, lists, counts, out, N);

    // aev fp32 dead after L1 fwd -> zero for its daev role
    hipMemsetAsync(daev, 0, (size_t)N * DAEV * sizeof(float), stream);

    // W3 -> o-layout (for L3 bwd)
    wconv_k<true, false><<<dim3(3, 3, 56), 256, 0, stream>>>(
        W3, Wh, Wl, nullptr, nullptr, 192, 160, 0);
    // L3 bwd: dh2 = (dh3 @ W3^T) * celu'  (in place in H2)
    mgemm_k<MODE_BWD, 0, 0, false, 1><<<dim3(2, rt, 56), 512, 0, stream>>>(
        H3h, H3l, Wh, Wl, nullptr, nullptr, H2h, H2l,
        lists, counts, N, 160, 160, 192, 160, 160, 192,
        (size_t)N * 160, (size_t)192 * 160, (size_t)N * 192);

    // W2 -> o-layout (for L2 bwd)
    wconv_k<true, false><<<dim3(3, 4, 56), 256, 0, stream>>>(
        W2, Wh, Wl, nullptr, nullptr, 256, 192, 0);
    // L2 bwd: dh1 = (dh2 @ W2^T) * celu'  (in place in H1)
    mgemm_k<MODE_BWD, 0, 0, false, 1><<<dim3(2, rt, 56), 512, 0, stream>>>(
        H2h, H2l, Wh, Wl, nullptr, nullptr, H1h, H1l,
        lists, counts, N, 192, 192, 256, 192, 192, 256,
        (size_t)N * 192, (size_t)256 * 192, (size_t)N * 256);

    // L1 bwd (m-concat K=2048, grid split-K x4 + in-block x2)
    mgemm_k<MODE_PLAIN, 0, 1, true, 4><<<dim3(8, rt, 28), 512, 0, stream>>>(
        H1h, H1l, W1, nullptr, nullptr, daev, nullptr, nullptr,
        lists, counts, N, 2048, 2048, 1008, 256, 256, 1008,
        0, 0, 0);

    radial_bwd_k<<<(P + 255) / 256, 256, 0, stream>>>(ai12, species, coords, daev, grad, P);
    angular_bwd_k<<<(T + 255) / 256, 256, 0, stream>>>(tri, species, coords, daev, grad, T);
    finalize_k<<<(N + 255) / 256, 256, 0, stream>>>(grad, sgp, sae, out, N);
}

// Round 10
// 777.813 us; speedup vs baseline: 1.0232x; 1.0232x over previous
//
#include <hip/hip_runtime.h>
#include <math.h>

// ---------------- problem constants (ANI-2x) ----------------
constexpr int SPEC = 7;
constexpr int DAEV = 1008;
constexpr int RADN = 112;
constexpr int H1W = 256, H2W = 192, H3W = 160;
constexpr int MENS = 8;
constexpr float ALPHA = 0.1f;
constexpr float RCR_ = 5.2f, RCA_ = 3.5f;
constexpr float ETAR = 19.7f, ETAA = 12.5f, ZETA_ = 14.1f;
constexpr float PIF = 3.14159265358979323846f;

enum { MODE_FWD = 0, MODE_BWD = 1, MODE_PLAIN = 2 };

typedef _Float16 f16x8 __attribute__((ext_vector_type(8)));
typedef float f32x4 __attribute__((ext_vector_type(4)));

__device__ __forceinline__ f32x4 mfma16(f16x8 a, f16x8 b, f32x4 c) {
    return __builtin_amdgcn_mfma_f32_16x16x32_f16(a, b, c, 0, 0, 0);
}

__device__ __forceinline__ void cvt8(float4 u0, float4 u1, f16x8& h, f16x8& l) {
    float x[8] = {u0.x, u0.y, u0.z, u0.w, u1.x, u1.y, u1.z, u1.w};
    #pragma unroll
    for (int e = 0; e < 8; ++e) {
        _Float16 hh = (_Float16)x[e];
        h[e] = hh;
        l[e] = (_Float16)(x[e] - (float)hh);
    }
}

// ---------------- species-list build ----------------
__global__ __launch_bounds__(256) void build_lists_k(
    const int* __restrict__ sgp, int* __restrict__ counts,
    int* __restrict__ lists, int N)
{
    int n = blockIdx.x * blockDim.x + threadIdx.x;
    if (n >= N) return;
    int g = sgp[n];
    if (g >= 0) {
        int p = atomicAdd(&counts[g], 1);
        lists[g * N + p] = n;
    }
}

// ---------------- row-tile plan: plan[0]=ntiles, plan[1+t]=(spec<<16)|tileIdx ----------------
__global__ void plan_k(const int* __restrict__ counts, int* __restrict__ plan)
{
    if (threadIdx.x == 0 && blockIdx.x == 0) {
        int nt = 0;
        for (int s = 0; s < SPEC; ++s) {
            int k = (counts[s] + 63) >> 6;
            for (int i = 0; i < k; ++i) plan[1 + nt++] = (s << 16) | i;
        }
        plan[0] = nt;
    }
}

// ---------------- AEV radial forward ----------------
__global__ __launch_bounds__(256) void radial_fwd_k(
    const int* __restrict__ ai12, const int* __restrict__ spec,
    const float* __restrict__ coord, float* __restrict__ aev, int P)
{
    int p = blockIdx.x * blockDim.x + threadIdx.x;
    if (p >= P) return;
    int i = ai12[p], j = ai12[P + p];
    float dx = coord[3 * j + 0] - coord[3 * i + 0];
    float dy = coord[3 * j + 1] - coord[3 * i + 1];
    float dz = coord[3 * j + 2] - coord[3 * i + 2];
    float d = sqrtf(dx * dx + dy * dy + dz * dz);
    float fc = (d < RCR_) ? (0.5f * cosf(PIF * d / RCR_) + 0.5f) : 0.f;
    int spi = spec[i], spj = spec[j];
    float* bi = aev + (size_t)i * DAEV + spj * 16;
    float* bj = aev + (size_t)j * DAEV + spi * 16;
    #pragma unroll
    for (int k = 0; k < 16; ++k) {
        float sh = 0.8f + 0.275f * k;
        float t = d - sh;
        float v = 0.25f * expf(-ETAR * t * t) * fc;
        atomicAdd(bi + k, v);
        atomicAdd(bj + k, v);
    }
}

// ---------------- AEV angular forward ----------------
__global__ __launch_bounds__(256) void angular_fwd_k(
    const int* __restrict__ tri, const int* __restrict__ spec,
    const float* __restrict__ coord, float* __restrict__ aev, int T)
{
    int t = blockIdx.x * blockDim.x + threadIdx.x;
    if (t >= T) return;
    int c = tri[t], a = tri[T + t], b = tri[2 * T + t];
    float cx = coord[3 * c], cy = coord[3 * c + 1], cz = coord[3 * c + 2];
    float v1x = coord[3 * a] - cx, v1y = coord[3 * a + 1] - cy, v1z = coord[3 * a + 2] - cz;
    float v2x = coord[3 * b] - cx, v2y = coord[3 * b + 1] - cy, v2z = coord[3 * b + 2] - cz;
    float d1 = sqrtf(v1x * v1x + v1y * v1y + v1z * v1z);
    float d2 = sqrtf(v2x * v2x + v2y * v2y + v2z * v2z);
    float u = v1x * v2x + v1y * v2y + v1z * v2z;
    float ca = 0.95f * u / (d1 * d2);
    float sa = sqrtf(fmaxf(1.f - ca * ca, 0.f));
    float fc1 = (d1 < RCA_) ? (0.5f * cosf(PIF * d1 / RCA_) + 0.5f) : 0.f;
    float fc2 = (d2 < RCA_) ? (0.5f * cosf(PIF * d2 / RCA_) + 0.5f) : 0.f;
    float fcj = fc1 * fc2;
    float savg = 0.5f * (d1 + d2);
    int s1 = spec[a], s2 = spec[b];
    int lo = min(s1, s2), hi = max(s1, s2);
    int pidx = lo * SPEC - (lo * (lo - 1)) / 2 + (hi - lo);
    float* ob = aev + (size_t)c * DAEV + RADN + pidx * 32;
    const float CZ[4] = {0.92387953f, 0.38268343f, -0.38268343f, -0.92387953f};
    const float SZ[4] = {0.38268343f, 0.92387953f, 0.92387953f, 0.38268343f};
    float f1[4];
    #pragma unroll
    for (int zz = 0; zz < 4; ++zz) {
        float cd = ca * CZ[zz] + sa * SZ[zz];
        float base = fmaxf(0.5f * (1.f + cd), 0.f);
        f1[zz] = powf(base, ZETA_);
    }
    #pragma unroll
    for (int q = 0; q < 8; ++q) {
        float sh = 0.8f + 0.3375f * q;
        float tq = savg - sh;
        float f2 = expf(-ETAA * tq * tq);
        float b2 = 2.f * f2 * fcj;
        #pragma unroll
        for (int zz = 0; zz < 4; ++zz)
            atomicAdd(ob + q * 4 + zz, b2 * f1[zz]);
    }
}

// ---------------- weight convert: fp32 -> hi/lo f16 ----------------
template<bool DO_O, bool DO_T>
__global__ __launch_bounds__(256) void wconv_k(
    const float* __restrict__ W,
    _Float16* __restrict__ oH, _Float16* __restrict__ oL,
    _Float16* __restrict__ tH, _Float16* __restrict__ tL,
    int K, int C, int ldt)
{
    __shared__ _Float16 sh[64][65];
    __shared__ _Float16 sl[64][65];
    const int z = blockIdx.z;
    const int k0 = blockIdx.y * 64, c0 = blockIdx.x * 64;
    const float* Wz = W + (size_t)z * K * C;
    const int c = threadIdx.x & 63, qr = threadIdx.x >> 6;
    #pragma unroll
    for (int rr = 0; rr < 16; ++rr) {
        int r = qr * 16 + rr;
        int k = k0 + r, cc = c0 + c;
        float v = (k < K && cc < C) ? Wz[(size_t)k * C + cc] : 0.f;
        _Float16 h = (_Float16)v;
        _Float16 l = (_Float16)(v - (float)h);
        if (DO_O && k < K && cc < C) {
            oH[(size_t)z * K * C + (size_t)k * C + cc] = h;
            oL[(size_t)z * K * C + (size_t)k * C + cc] = l;
        }
        if (DO_T) { sh[r][c] = h; sl[r][c] = l; }
    }
    if (DO_T) {
        __syncthreads();
        #pragma unroll
        for (int rr = 0; rr < 16; ++rr) {
            int r = qr * 16 + rr;
            int crow = c0 + r, kcol = k0 + c;
            if (crow < C && kcol < ldt) {
                tH[(size_t)z * C * ldt + (size_t)crow * ldt + kcol] = sh[c][r];
                tL[(size_t)z * C * ldt + (size_t)crow * ldt + kcol] = sl[c][r];
            }
        }
    }
}

// ---------------- MFMA fp16x3-split GEMM, compacted grid ----------------
// Block 64 rows x 128 cols; 512 threads = 2 k-groups x 4 waves (32x64 each).
// Grid: non-MCONCAT (colTiles, TILE_SLOTS, MENS=8): y -> plan tile (spec,row0),
//       z -> ensemble m; weight index zW = m*SPEC+spec.  XCD swizzle on z=8.
// MCONCAT (colTiles, TILE_SLOTS, SPLITK): z -> K chunk.
template<int MODE, int ASRC, int BSRC, bool MCONCAT, int SPLITK>
__global__ __launch_bounds__(512) void mgemm_k(
    const void* __restrict__ Ah_, const void* __restrict__ Al_,
    const void* __restrict__ Bh_, const void* __restrict__ Bl_,
    const float* __restrict__ bias, float* __restrict__ cF,
    _Float16* __restrict__ cH, _Float16* __restrict__ cL,
    const int* __restrict__ plan,
    const int* __restrict__ lists, const int* __restrict__ counts,
    int N, int K, int KA, int H, int lda, int ldb, int ldc,
    size_t aStrM, size_t bStrZ, size_t cStrM)
{
    __shared__ f16x8 SM[3072];
    __shared__ int atomsS[64];
    #define AhS(g, kq, i) SM[(g) * 256 + (kq) * 64 + (i)]
    #define AlS(g, kq, i) SM[512 + (g) * 256 + (kq) * 64 + (i)]
    #define BhS(g, kq, c) SM[1024 + (g) * 512 + (kq) * 128 + (c)]
    #define BlS(g, kq, c) SM[2048 + (g) * 512 + (kq) * 128 + (c)]

    int bx = blockIdx.x, by = blockIdx.y, bz = blockIdx.z;
    if (!MCONCAT && gridDim.z == 8) {        // XCD swizzle: ensemble m -> one XCD
        int flat = bx + gridDim.x * (by + gridDim.y * bz);
        bz = flat & 7;
        int rest = flat >> 3;
        bx = rest % gridDim.x;
        by = rest / gridDim.x;
    }

    const int ntiles = plan[0];
    if (by >= ntiles) return;
    const int ent = plan[1 + by];
    const int sp_ = ent >> 16;
    const int row0 = (ent & 0xffff) << 6;
    int m, chunk, zW;
    if (MCONCAT) { m = 0; chunk = bz; zW = 0; }
    else { m = bz; chunk = 0; zW = m * SPEC + sp_; }

    const int cnt = counts[sp_];
    if (row0 >= cnt) return;
    const int col0 = bx * 128;
    const int tid = threadIdx.x;
    const int w = tid >> 6, lane = tid & 63;
    const int g = w >> 2, wl = w & 3;

    const int rA = min(row0 + lane, cnt - 1);
    const int atomA = lists[sp_ * N + rA];
    if (tid < 64) atomsS[tid] = atomA;

    const int bc0 = min(col0 + lane, H - 1);
    const int bc1 = min(col0 + 64 + lane, H - 1);

    f16x8 rAh, rAl;
    float4 rAf0, rAf1;
    f16x8 rBh0, rBl0, rBh1, rBl1;
    float4 rBq[4];
    float rB0f[8], rB1f[8];

    auto LOAD = [&](int k0s) {
        int kk = k0s + wl * 8;
        // ---- A ----
        if constexpr (ASRC == 0) {
            const _Float16* ah = (const _Float16*)Ah_;
            const _Float16* al = (const _Float16*)Al_;
            size_t ao;
            if constexpr (MCONCAT) {
                int mm = kk >> 8, kr = kk & 255;
                ao = ((size_t)mm * N + atomA) * (size_t)lda + kr;
            } else {
                ao = (size_t)m * aStrM + (size_t)atomA * lda + kk;
            }
            rAh = *(const f16x8*)(ah + ao);
            rAl = *(const f16x8*)(al + ao);
        } else {
            const float* af = (const float*)Ah_;
            if (kk < KA) {
                const float* p = af + (size_t)atomA * lda + kk;
                rAf0 = *(const float4*)p;
                rAf1 = *(const float4*)(p + 4);
            } else {
                rAf0 = make_float4(0.f, 0.f, 0.f, 0.f);
                rAf1 = rAf0;
            }
        }
        // ---- B ----
        if constexpr (BSRC == 0) {
            const _Float16* bh = (const _Float16*)Bh_;
            const _Float16* bl = (const _Float16*)Bl_;
            size_t b0 = (size_t)zW * bStrZ + (size_t)bc0 * ldb + kk;
            size_t b1 = (size_t)zW * bStrZ + (size_t)bc1 * ldb + kk;
            rBh0 = *(const f16x8*)(bh + b0);
            rBh1 = *(const f16x8*)(bh + b1);
            rBl0 = *(const f16x8*)(bl + b0);
            rBl1 = *(const f16x8*)(bl + b1);
        } else if constexpr (BSRC == 1) {
            const float* bf = (const float*)Bh_;
            int mm = kk >> 8, kr = kk & 255;   // MCONCAT layout
            size_t b0 = ((size_t)(mm * SPEC + sp_) * DAEV + bc0) * (size_t)ldb + kr;
            size_t b1 = ((size_t)(mm * SPEC + sp_) * DAEV + bc1) * (size_t)ldb + kr;
            rBq[0] = *(const float4*)(bf + b0);
            rBq[1] = *(const float4*)(bf + b0 + 4);
            rBq[2] = *(const float4*)(bf + b1);
            rBq[3] = *(const float4*)(bf + b1 + 4);
        } else {
            // fp32 [k][c]: lane=col -> coalesced 256B segments per k
            const float* bf = (const float*)Bh_ + (size_t)zW * bStrZ;
            #pragma unroll
            for (int j = 0; j < 8; ++j) {
                int kg = kk + j;
                float v0 = 0.f, v1 = 0.f;
                if (kg < KA) {
                    v0 = bf[(size_t)kg * ldb + bc0];
                    v1 = bf[(size_t)kg * ldb + bc1];
                }
                rB0f[j] = v0;
                rB1f[j] = v1;
            }
        }
    };

    auto WRITE = [&]() {
        if constexpr (ASRC == 0) {
            AhS(g, wl, lane) = rAh;
            AlS(g, wl, lane) = rAl;
        } else {
            f16x8 h, l;
            cvt8(rAf0, rAf1, h, l);
            AhS(g, wl, lane) = h;
            AlS(g, wl, lane) = l;
        }
        if constexpr (BSRC == 0) {
            BhS(g, wl, lane) = rBh0;
            BhS(g, wl, 64 + lane) = rBh1;
            BlS(g, wl, lane) = rBl0;
            BlS(g, wl, 64 + lane) = rBl1;
        } else if constexpr (BSRC == 1) {
            f16x8 h, l;
            cvt8(rBq[0], rBq[1], h, l);
            BhS(g, wl, lane) = h;
            BlS(g, wl, lane) = l;
            cvt8(rBq[2], rBq[3], h, l);
            BhS(g, wl, 64 + lane) = h;
            BlS(g, wl, 64 + lane) = l;
        } else {
            f16x8 h0, l0, h1, l1;
            #pragma unroll
            for (int j = 0; j < 8; ++j) {
                _Float16 ha = (_Float16)rB0f[j];
                h0[j] = ha; l0[j] = (_Float16)(rB0f[j] - (float)ha);
                _Float16 hb = (_Float16)rB1f[j];
                h1[j] = hb; l1[j] = (_Float16)(rB1f[j] - (float)hb);
            }
            BhS(g, wl, lane) = h0;
            BlS(g, wl, lane) = l0;
            BhS(g, wl, 64 + lane) = h1;
            BlS(g, wl, 64 + lane) = l1;
        }
    };

    const int wr = wl >> 1, wc = wl & 1;
    const int fr = lane & 15, q = lane >> 4;

    f32x4 acc[2][4];
    #pragma unroll
    for (int mi = 0; mi < 2; ++mi)
        #pragma unroll
        for (int ni = 0; ni < 4; ++ni)
            acc[mi][ni] = (f32x4){0.f, 0.f, 0.f, 0.f};

    const int KC = (SPLITK > 1) ? (K / SPLITK) : K;
    const int kbeg = chunk * KC;
    const int ntT = KC / 32;
    const int nt0 = (ntT + 1) >> 1;
    const int my_nt = g ? (ntT - nt0) : nt0;
    const int gk = kbeg + (g ? nt0 * 32 : 0);

    if (my_nt > 0) LOAD(gk);

    for (int t = 0; t < nt0; ++t) {
        __syncthreads();
        if (t < my_nt) WRITE();
        __syncthreads();
        if (t + 1 < my_nt) LOAD(gk + (t + 1) * 32);

        if (t < my_nt) {
            f16x8 fah[2], fal[2], fbh[4], fbl[4];
            #pragma unroll
            for (int mi = 0; mi < 2; ++mi) {
                int r = wr * 32 + mi * 16 + fr;
                fah[mi] = AhS(g, q, r);
                fal[mi] = AlS(g, q, r);
            }
            #pragma unroll
            for (int ni = 0; ni < 4; ++ni) {
                int c = wc * 64 + ni * 16 + fr;
                fbh[ni] = BhS(g, q, c);
                fbl[ni] = BlS(g, q, c);
            }
            #pragma unroll
            for (int mi = 0; mi < 2; ++mi)
                #pragma unroll
                for (int ni = 0; ni < 4; ++ni) {
                    acc[mi][ni] = mfma16(fah[mi], fbl[ni], acc[mi][ni]);
                    acc[mi][ni] = mfma16(fal[mi], fbh[ni], acc[mi][ni]);
                    acc[mi][ni] = mfma16(fah[mi], fbh[ni], acc[mi][ni]);
                }
        }
    }

    // ---- combine the two k-groups' partial accumulators via LDS ----
    __syncthreads();
    f32x4* X = (f32x4*)SM;
    const int xbase = (wl * 64 + lane) * 8;
    if (g == 1) {
        #pragma unroll
        for (int mi = 0; mi < 2; ++mi)
            #pragma unroll
            for (int ni = 0; ni < 4; ++ni)
                X[xbase + mi * 4 + ni] = acc[mi][ni];
    }
    __syncthreads();
    if (g == 1) return;
    #pragma unroll
    for (int mi = 0; mi < 2; ++mi)
        #pragma unroll
        for (int ni = 0; ni < 4; ++ni)
            acc[mi][ni] += X[xbase + mi * 4 + ni];

    // ---- epilogue (group 0 only) ----
    const float* brow = (MODE == MODE_FWD) ? (bias + (size_t)zW * H) : nullptr;
    #pragma unroll
    for (int mi = 0; mi < 2; ++mi) {
        #pragma unroll
        for (int r = 0; r < 4; ++r) {
            int rl = wr * 32 + mi * 16 + q * 4 + r;
            if (row0 + rl >= cnt) continue;
            int atom = atomsS[rl];
            size_t rowoff = (size_t)m * cStrM + (size_t)atom * ldc;
            #pragma unroll
            for (int ni = 0; ni < 4; ++ni) {
                int col = col0 + wc * 64 + ni * 16 + fr;
                if (col >= H) continue;
                float v = acc[mi][ni][r];
                size_t idx = rowoff + col;
                if (MODE == MODE_FWD) {
                    v += brow[col];
                    v = (v > 0.f) ? v : ALPHA * expm1f(v * (1.f / ALPHA));
                    _Float16 hh = (_Float16)v;
                    cH[idx] = hh;
                    cL[idx] = (_Float16)(v - (float)hh);
                } else if (MODE == MODE_BWD) {
                    float hprev = (float)cH[idx] + (float)cL[idx];
                    float D = (hprev > 0.f) ? 1.f : (hprev * (1.f / ALPHA) + 1.f);
                    v *= D;
                    _Float16 hh = (_Float16)v;
                    cH[idx] = hh;
                    cL[idx] = (_Float16)(v - (float)hh);
                } else {
                    if (SPLITK > 1) atomicAdd(cF + idx, v);
                    else cF[idx] = v;
                }
            }
        }
    }
    #undef AhS
    #undef AlS
    #undef BhS
    #undef BlS
}

// ---------------- layer-4 dot + energy + dh3 (in place) ----------------
__global__ __launch_bounds__(256) void l4_k(
    _Float16* __restrict__ h3H, _Float16* __restrict__ h3L,
    const float* __restrict__ W4, const float* __restrict__ b4,
    const int* __restrict__ lists, const int* __restrict__ counts,
    float* __restrict__ Eout, int N)
{
    const int z = blockIdx.y;
    const int m = z / SPEC, s = z - m * SPEC;
    const int cnt = counts[s];
    const int sub = threadIdx.x >> 3;
    const int l8 = threadIdx.x & 7;
    const int row = blockIdx.x * 32 + sub;

    __shared__ float bsum;
    if (threadIdx.x == 0) bsum = 0.f;
    __syncthreads();

    if (row < cnt) {
        int atom = lists[s * N + row];
        size_t base = ((size_t)m * N + atom) * H3W;
        const float* w4 = W4 + (size_t)z * H3W;
        float sum = 0.f;
        for (int k = l8; k < H3W; k += 8) {
            float h = (float)h3H[base + k] + (float)h3L[base + k];
            float wv = w4[k];
            sum += h * wv;
            float D = (h > 0.f) ? 1.f : (h * 10.f + 1.f);
            float g = 0.125f * wv * D;
            _Float16 gh = (_Float16)g;
            h3H[base + k] = gh;
            h3L[base + k] = (_Float16)(g - (float)gh);
        }
        sum += __shfl_xor(sum, 1);
        sum += __shfl_xor(sum, 2);
        sum += __shfl_xor(sum, 4);
        if (l8 == 0) atomicAdd(&bsum, sum + b4[z]);
    }
    __syncthreads();
    if (threadIdx.x == 0) atomicAdd(Eout, 0.125f * bsum);
}

// ---------------- AEV radial backward ----------------
__global__ __launch_bounds__(256) void radial_bwd_k(
    const int* __restrict__ ai12, const int* __restrict__ spec,
    const float* __restrict__ coord, const float* __restrict__ daev,
    float* __restrict__ grad, int P)
{
    int p = blockIdx.x * blockDim.x + threadIdx.x;
    if (p >= P) return;
    int i = ai12[p], j = ai12[P + p];
    float dx = coord[3 * j + 0] - coord[3 * i + 0];
    float dy = coord[3 * j + 1] - coord[3 * i + 1];
    float dz = coord[3 * j + 2] - coord[3 * i + 2];
    float d = sqrtf(dx * dx + dy * dy + dz * dz);
    float fc, dfc;
    if (d < RCR_) {
        float ph = PIF * d / RCR_;
        fc = 0.5f * cosf(ph) + 0.5f;
        dfc = -0.5f * sinf(ph) * (PIF / RCR_);
    } else { fc = 0.f; dfc = 0.f; }
    int spi = spec[i], spj = spec[j];
    const float* gi = daev + (size_t)i * DAEV + spj * 16;
    const float* gj = daev + (size_t)j * DAEV + spi * 16;
    float gs = 0.f;
    #pragma unroll
    for (int k = 0; k < 16; ++k) {
        float sh = 0.8f + 0.275f * k;
        float t = d - sh;
        float ex = expf(-ETAR * t * t);
        float g = gi[k] + gj[k];
        gs += g * 0.25f * ex * (dfc - 2.f * ETAR * t * fc);
    }
    float invd = 1.f / d;
    float gx = gs * dx * invd, gy = gs * dy * invd, gz = gs * dz * invd;
    atomicAdd(&grad[3 * j + 0], gx);  atomicAdd(&grad[3 * j + 1], gy);  atomicAdd(&grad[3 * j + 2], gz);
    atomicAdd(&grad[3 * i + 0], -gx); atomicAdd(&grad[3 * i + 1], -gy); atomicAdd(&grad[3 * i + 2], -gz);
}

// ---------------- AEV angular backward ----------------
__global__ __launch_bounds__(256) void angular_bwd_k(
    const int* __restrict__ tri, const int* __restrict__ spec,
    const float* __restrict__ coord, const float* __restrict__ daev,
    float* __restrict__ grad, int T)
{
    int t = blockIdx.x * blockDim.x + threadIdx.x;
    if (t >= T) return;
    int c = tri[t], a = tri[T + t], b = tri[2 * T + t];
    float cx = coord[3 * c], cy = coord[3 * c + 1], cz = coord[3 * c + 2];
    float v1x = coord[3 * a] - cx, v1y = coord[3 * a + 1] - cy, v1z = coord[3 * a + 2] - cz;
    float v2x = coord[3 * b] - cx, v2y = coord[3 * b + 1] - cy, v2z = coord[3 * b + 2] - cz;
    float d1 = sqrtf(v1x * v1x + v1y * v1y + v1z * v1z);
    float d2 = sqrtf(v2x * v2x + v2y * v2y + v2z * v2z);
    float u = v1x * v2x + v1y * v2y + v1z * v2z;
    float inv12 = 1.f / (d1 * d2);
    float ca = 0.95f * u * inv12;
    float sa = sqrtf(fmaxf(1.f - ca * ca, 1e-12f));
    float fc1, dfc1, fc2, dfc2;
    if (d1 < RCA_) {
        float ph = PIF * d1 / RCA_;
        fc1 = 0.5f * cosf(ph) + 0.5f;
        dfc1 = -0.5f * sinf(ph) * (PIF / RCA_);
    } else { fc1 = 0.f; dfc1 = 0.f; }
    if (d2 < RCA_) {
        float ph = PIF * d2 / RCA_;
        fc2 = 0.5f * cosf(ph) + 0.5f;
        dfc2 = -0.5f * sinf(ph) * (PIF / RCA_);
    } else { fc2 = 0.f; dfc2 = 0.f; }
    float fcj = fc1 * fc2;
    float savg = 0.5f * (d1 + d2);
    int s1 = spec[a], s2 = spec[b];
    int lo = min(s1, s2), hi = max(s1, s2);
    int pidx = lo * SPEC - (lo * (lo - 1)) / 2 + (hi - lo);
    const float* gb = daev + (size_t)c * DAEV + RADN + pidx * 32;
    const float CZ[4] = {0.92387953f, 0.38268343f, -0.38268343f, -0.92387953f};
    const float SZ[4] = {0.38268343f, 0.92387953f, 0.92387953f, 0.38268343f};
    float f1[4], df1[4];
    #pragma unroll
    for (int zz = 0; zz < 4; ++zz) {
        float cd = ca * CZ[zz] + sa * SZ[zz];
        float sd = sa * CZ[zz] - ca * SZ[zz];
        float base = fmaxf(0.5f * (1.f + cd), 0.f);
        float pm1 = powf(base, ZETA_ - 1.f);
        f1[zz] = pm1 * base;
        df1[zz] = ZETA_ * pm1 * (-0.5f * sd);
    }
    float A_ = 0.f, B_ = 0.f, Cc = 0.f;
    #pragma unroll
    for (int q = 0; q < 8; ++q) {
        float sh = 0.8f + 0.3375f * q;
        float tq = savg - sh;
        float f2 = expf(-ETAA * tq * tq);
        float df2 = -ETAA * tq * f2;
        #pragma unroll
        for (int zz = 0; zz < 4; ++zz) {
            float G2 = 2.f * gb[q * 4 + zz];
            A_ += G2 * f2 * df1[zz];
            B_ += G2 * df2 * f1[zz];
            Cc += G2 * f2 * f1[zz];
        }
    }
    A_ *= fcj; B_ *= fcj;
    float C1 = Cc * dfc1 * fc2;
    float C2 = Cc * fc1 * dfc2;
    float cA = -A_ / sa;
    float k12 = cA * 0.95f * inv12;
    float coef1 = (cA * (-ca) / d1 + B_ + C1) / d1;
    float coef2 = (cA * (-ca) / d2 + B_ + C2) / d2;
    float g1x = coef1 * v1x + k12 * v2x;
    float g1y = coef1 * v1y + k12 * v2y;
    float g1z = coef1 * v1z + k12 * v2z;
    float g2x = coef2 * v2x + k12 * v1x;
    float g2y = coef2 * v2y + k12 * v1y;
    float g2z = coef2 * v2z + k12 * v1z;
    atomicAdd(&grad[3 * a + 0], g1x); atomicAdd(&grad[3 * a + 1], g1y); atomicAdd(&grad[3 * a + 2], g1z);
    atomicAdd(&grad[3 * b + 0], g2x); atomicAdd(&grad[3 * b + 1], g2y); atomicAdd(&grad[3 * b + 2], g2z);
    atomicAdd(&grad[3 * c + 0], -(g1x + g2x));
    atomicAdd(&grad[3 * c + 1], -(g1y + g2y));
    atomicAdd(&grad[3 * c + 2], -(g1z + g2z));
}

// ---------------- finalize: forces out, SAE into E ----------------
__global__ __launch_bounds__(256) void finalize_k(
    const float* __restrict__ grad, const int* __restrict__ sgp,
    const float* __restrict__ sae, float* __restrict__ out, int N)
{
    int n = blockIdx.x * blockDim.x + threadIdx.x;
    __shared__ float bs;
    if (threadIdx.x == 0) bs = 0.f;
    __syncthreads();
    float v = 0.f;
    if (n < N) {
        out[1 + 3 * n + 0] = -grad[3 * n + 0];
        out[1 + 3 * n + 1] = -grad[3 * n + 1];
        out[1 + 3 * n + 2] = -grad[3 * n + 2];
        int g = sgp[n];
        if (g >= 0) v = sae[g];
    }
    atomicAdd(&bs, v);
    __syncthreads();
    if (threadIdx.x == 0) atomicAdd(out, bs);
}

// ---------------- host launch ----------------
extern "C" void kernel_launch(void* const* d_in, const int* in_sizes, int n_in,
                              void* d_out, int out_size, void* d_ws, size_t ws_size,
                              hipStream_t stream)
{
    (void)n_in; (void)out_size; (void)ws_size;
    const int* species = (const int*)d_in[0];
    const float* coords = (const float*)d_in[1];
    const int* ai12 = (const int*)d_in[2];
    const int* tri = (const int*)d_in[3];
    const int* sgp = (const int*)d_in[4];
    const float* W1 = (const float*)d_in[5];
    const float* b1 = (const float*)d_in[6];
    const float* W2 = (const float*)d_in[7];
    const float* b2 = (const float*)d_in[8];
    const float* W3 = (const float*)d_in[9];
    const float* b3 = (const float*)d_in[10];
    const float* W4 = (const float*)d_in[11];
    const float* b4 = (const float*)d_in[12];
    const float* sae = (const float*)d_in[13];
    float* out = (float*)d_out;

    const int N = in_sizes[0];
    const int P = in_sizes[2] / 2;
    const int T = in_sizes[3] / 3;
    const size_t NM = (size_t)MENS * N;

    float* ws = (float*)d_ws;
    size_t off = 0;
    auto alloc = [&](size_t nf) { float* p = ws + off; off += nf; return p; };

    // total ~75.6 MB == proven-safe footprint
    float* aev = alloc((size_t)N * DAEV);              // reused as daev after L1 fwd
    _Float16* H1h = (_Float16*)alloc(NM * 128);        // d1 written in place
    _Float16* H1l = (_Float16*)alloc(NM * 128);
    _Float16* H2h = (_Float16*)alloc(NM * 96);         // d2 in place
    _Float16* H2l = (_Float16*)alloc(NM * 96);
    _Float16* H3h = (_Float16*)alloc(NM * 80);         // d3 in place
    _Float16* H3l = (_Float16*)alloc(NM * 80);
    _Float16* Wh = (_Float16*)alloc((size_t)56 * 96 * 256);
    _Float16* Wl = (_Float16*)alloc((size_t)56 * 96 * 256);
    float* grad = alloc((size_t)N * 3);
    int* counts = (int*)alloc(8);
    int* plan = (int*)alloc(64);
    int* lists = (int*)alloc((size_t)SPEC * N);
    float* daev = aev;

    hipMemsetAsync(aev, 0, (size_t)N * DAEV * sizeof(float), stream);
    hipMemsetAsync(grad, 0, (size_t)N * 3 * sizeof(float), stream);
    hipMemsetAsync(counts, 0, 8 * sizeof(int), stream);
    hipMemsetAsync(d_out, 0, sizeof(float), stream);

    build_lists_k<<<(N + 255) / 256, 256, 0, stream>>>(sgp, counts, lists, N);
    plan_k<<<1, 64, 0, stream>>>(counts, plan);
    radial_fwd_k<<<(P + 255) / 256, 256, 0, stream>>>(ai12, species, coords, aev, P);
    angular_fwd_k<<<(T + 255) / 256, 256, 0, stream>>>(tri, species, coords, aev, T);

    const int YT = (N + 63) / 64 + SPEC;   // upper bound on total live row-tiles

    // L1 fwd: H1 = celu(AEV @ W1 + b1); A fp32 (aev), B fp32 W1 [k][c]
    mgemm_k<MODE_FWD, 1, 2, false, 1><<<dim3(2, YT, 8), 512, 0, stream>>>(
        aev, nullptr, W1, nullptr, b1, nullptr, H1h, H1l, plan,
        lists, counts, N, 1024, 1008, 256, 1008, 256, 256,
        0, (size_t)1008 * 256, (size_t)N * 256);

    // W2 -> t-layout (for L2 fwd)
    wconv_k<false, true><<<dim3(3, 4, 56), 256, 0, stream>>>(
        W2, nullptr, nullptr, Wh, Wl, 256, 192, 256);
    // L2 fwd
    mgemm_k<MODE_FWD, 0, 0, false, 1><<<dim3(2, YT, 8), 512, 0, stream>>>(
        H1h, H1l, Wh, Wl, b2, nullptr, H2h, H2l, plan,
        lists, counts, N, 256, 256, 192, 256, 256, 192,
        (size_t)N * 256, (size_t)192 * 256, (size_t)N * 192);

    // W3 -> t-layout (for L3 fwd)
    wconv_k<false, true><<<dim3(3, 3, 56), 256, 0, stream>>>(
        W3, nullptr, nullptr, Wh, Wl, 192, 160, 192);
    // L3 fwd
    mgemm_k<MODE_FWD, 0, 0, false, 1><<<dim3(2, YT, 8), 512, 0, stream>>>(
        H2h, H2l, Wh, Wl, b3, nullptr, H3h, H3l, plan,
        lists, counts, N, 192, 192, 160, 192, 192, 160,
        (size_t)N * 192, (size_t)160 * 192, (size_t)N * 160);

    // L4 + dh3 (in place in H3)
    l4_k<<<dim3((N + 31) / 32, 56), 256, 0, stream>>>(
        H3h, H3l, W4, b4, lists, counts, out, N);

    // aev fp32 dead after L1 fwd -> zero for its daev role
    hipMemsetAsync(daev, 0, (size_t)N * DAEV * sizeof(float), stream);

    // W3 -> o-layout (for L3 bwd)
    wconv_k<true, false><<<dim3(3, 3, 56), 256, 0, stream>>>(
        W3, Wh, Wl, nullptr, nullptr, 192, 160, 0);
    // L3 bwd: dh2 = (dh3 @ W3^T) * celu'  (in place in H2)
    mgemm_k<MODE_BWD, 0, 0, false, 1><<<dim3(2, YT, 8), 512, 0, stream>>>(
        H3h, H3l, Wh, Wl, nullptr, nullptr, H2h, H2l, plan,
        lists, counts, N, 160, 160, 192, 160, 160, 192,
        (size_t)N * 160, (size_t)192 * 160, (size_t)N * 192);

    // W2 -> o-layout (for L2 bwd)
    wconv_k<true, false><<<dim3(3, 4, 56), 256, 0, stream>>>(
        W2, Wh, Wl, nullptr, nullptr, 256, 192, 0);
    // L2 bwd: dh1 = (dh2 @ W2^T) * celu'  (in place in H1)
    mgemm_k<MODE_BWD, 0, 0, false, 1><<<dim3(2, YT, 8), 512, 0, stream>>>(
        H2h, H2l, Wh, Wl, nullptr, nullptr, H1h, H1l, plan,
        lists, counts, N, 192, 192, 256, 192, 192, 256,
        (size_t)N * 192, (size_t)256 * 192, (size_t)N * 256);

    // L1 bwd (m-concat K=2048, grid split-K x4 + in-block x2)
    mgemm_k<MODE_PLAIN, 0, 1, true, 4><<<dim3(8, YT, 4), 512, 0, stream>>>(
        H1h, H1l, W1, nullptr, nullptr, daev, nullptr, nullptr, plan,
        lists, counts, N, 2048, 2048, 1008, 256, 256, 1008,
        0, 0, 0);

    radial_bwd_k<<<(P + 255) / 256, 256, 0, stream>>>(ai12, species, coords, daev, grad, P);
    angular_bwd_k<<<(T + 255) / 256, 256, 0, stream>>>(tri, species, coords, daev, grad, T);
    finalize_k<<<(N + 255) / 256, 256, 0, stream>>>(grad, sgp, sae, out, N);
}